// Round 1
// baseline (128.073 us; speedup 1.0000x reference)
//
#include <hip/hip_runtime.h>
#include <math.h>

#define NN 512
#define DD 256

// ---------- f64 wave/block reductions ----------
__device__ __forceinline__ double wred_sum(double v){
  #pragma unroll
  for (int o = 32; o > 0; o >>= 1) v += __shfl_down(v, o);
  return v;
}
// 256-thread (4-wave) block sum
__device__ double bred_sum(double v){
  __shared__ double s[4]; __shared__ double r;
  int lane = threadIdx.x & 63, w = threadIdx.x >> 6;
  v = wred_sum(v);
  __syncthreads();
  if (lane == 0) s[w] = v;
  __syncthreads();
  if (threadIdx.x == 0) r = (s[0] + s[1]) + (s[2] + s[3]);
  __syncthreads();
  return r;
}
// 256-thread dual-channel block sum (one barrier set for two values)
__device__ void bred_sum2(double& a, double& b){
  __shared__ double sa[4], sb[4]; __shared__ double ra, rb;
  int lane = threadIdx.x & 63, w = threadIdx.x >> 6;
  #pragma unroll
  for (int o = 32; o > 0; o >>= 1){
    a += __shfl_down(a, o);
    b += __shfl_down(b, o);
  }
  __syncthreads();
  if (lane == 0){ sa[w] = a; sb[w] = b; }
  __syncthreads();
  if (threadIdx.x == 0){
    ra = (sa[0] + sa[1]) + (sa[2] + sa[3]);
    rb = (sb[0] + sb[1]) + (sb[2] + sb[3]);
  }
  __syncthreads();
  a = ra; b = rb;
}

__device__ __forceinline__ double artanh_clip(double x){
  const double lim = 1.0 - 1e-5;           // BALL_EPS
  if (x >  lim) x =  lim;
  if (x < -lim) x = -lim;
  return 0.5 * log((1.0 + x) / (1.0 - x));
}

// ---------- K1: expmap0 (f32 out, f64 norm) ----------
__global__ __launch_bounds__(256) void expmap_k(const float* __restrict__ u, float* __restrict__ H){
  int i = blockIdx.x, t = threadIdx.x;
  float x = u[i * DD + t];
  double n2 = bred_sum((double)x * (double)x);
  double n = sqrt(n2); if (n < 1e-15) n = 1e-15;
  H[i * DD + t] = (float)(tanh(n) / n * (double)x);
}

// ---------- K2: Wh = mobius_matvec(W, H); r2 = ||Wh||^2 (f64) ----------
__global__ __launch_bounds__(256) void matvec_k(const float* __restrict__ H, const float* __restrict__ W,
                         float* __restrict__ Wh, double* __restrict__ r2){
  int i = blockIdx.x, t = threadIdx.x;
  __shared__ float hrow[DD];
  float h = H[i * DD + t];
  hrow[t] = h;
  __syncthreads();
  const float4* Wt = (const float4*)(W + t * DD);   // Mx[t] = sum_k H[k]*W[t][k]
  const float4* hr = (const float4*)hrow;
  float a0 = 0.f, a1 = 0.f, a2 = 0.f, a3 = 0.f;
  #pragma unroll 8
  for (int k = 0; k < DD / 4; k++){
    float4 w = Wt[k], x = hr[k];
    a0 = fmaf(x.x, w.x, a0); a1 = fmaf(x.y, w.y, a1);
    a2 = fmaf(x.z, w.z, a2); a3 = fmaf(x.w, w.w, a3);
  }
  float mx = (a0 + a1) + (a2 + a3);
  // fused dual reduction: 3 barriers instead of 6
  double xn2  = (double)h  * (double)h;
  double mxn2 = (double)mx * (double)mx;
  bred_sum2(xn2, mxn2);
  double xn  = sqrt(xn2);  if (xn  < 1e-15) xn  = 1e-15;
  double mxn = sqrt(mxn2); if (mxn < 1e-15) mxn = 1e-15;
  double th = tanh(mxn / xn * artanh_clip(xn));
  Wh[i * DD + t] = (float)(mx * (th / mxn));
  if (t == 0) r2[i] = th * th;             // exact ||Wh_i||^2
}

// ---------- K3: fused Gram-tile + score epilogue (f64) + softmax ----------
// 512 threads (8 waves/CU). Block b owns rows i0=2b, i1=2b+1.
// Thread tid: r = tid>>8 (row), c = tid&255 → scores (i0+r, c) and (i0+r, c+256).
// Fixed-shift softmax (scores bounded by d^2 <= (2*artanh(1-1e-5))^2 < 150):
// exp(v-150) never overflows/underflows in f64 → max-reduction eliminated.
__global__ __launch_bounds__(512) void scores_k(const float* __restrict__ Wh, const double* __restrict__ r2,
                         const int* __restrict__ A, float* __restrict__ att){
  int b = blockIdx.x, tid = threadIdx.x;
  int i0 = 2 * b;
  int r = tid >> 8, c = tid & 255;
  __shared__ float xs[2 * DD];
  xs[tid] = Wh[i0 * DD + tid];             // rows i0,i1 contiguous
  __syncthreads();
  int i = i0 + r;
  int j0 = c, j1 = c + DD;
  const float4* xr  = (const float4*)(xs + r * DD);
  const float4* wj0 = (const float4*)(Wh + j0 * DD);
  const float4* wj1 = (const float4*)(Wh + j1 * DD);
  // two dots, split into two loops to halve live L1 streams per wave
  float4 s0 = {0,0,0,0};
  #pragma unroll 8
  for (int k = 0; k < DD / 4; k++){
    float4 p = xr[k], a = wj0[k];
    s0.x = fmaf(p.x, a.x, s0.x); s0.y = fmaf(p.y, a.y, s0.y);
    s0.z = fmaf(p.z, a.z, s0.z); s0.w = fmaf(p.w, a.w, s0.w);
  }
  float4 s1 = {0,0,0,0};
  #pragma unroll 8
  for (int k = 0; k < DD / 4; k++){
    float4 p = xr[k], a = wj1[k];
    s1.x = fmaf(p.x, a.x, s1.x); s1.y = fmaf(p.y, a.y, s1.y);
    s1.z = fmaf(p.z, a.z, s1.z); s1.w = fmaf(p.w, a.w, s1.w);
  }
  double d0 = (double)((s0.x + s0.y) + (s0.z + s0.w));
  double d1 = (double)((s1.x + s1.y) + (s1.z + s1.w));

  double X2 = r2[i];
  double Y0 = r2[j0], Y1 = r2[j1];

  auto score = [&](double dot, double X2d, double Y2, int jj) -> double {
    if (i == jj) return 0.0;               // exact: mobius_add(-x,x)=0
    double xy = -dot;
    double a  = 1.0 + 2.0 * xy + Y2;
    double bb = 1.0 - X2d;
    double den = 1.0 + 2.0 * xy + X2d * Y2;
    if (den < 1e-15) den = 1e-15;
    double nn = a * a * X2d + 2.0 * a * bb * xy + bb * bb * Y2;
    if (nn < 0.0) nn = 0.0;
    double s = sqrt(nn);
    double smax = den * (1.0 - 1e-5);      // clip artanh arg at 1-1e-5
    if (s > smax) s = smax;
    double d = log((den + s) / (den - s)); // = 2*artanh(s/den), one div
    return d * d;
  };

  int m0 = A[i * NN + j0], m1 = A[i * NN + j1];
  double e0 = 0.0, e1 = 0.0;
  if (m0) e0 = exp(score(d0, X2, Y0, j0) - 150.0);
  if (m1) e1 = exp(score(d1, X2, Y1, j1) - 150.0);

  // per-row sum: wave reduce + 4-wave LDS combine (waves 0-3 = row0, 4-7 = row1)
  double part = wred_sum(e0 + e1);
  __shared__ double ssum[8];
  int w = tid >> 6, lane = tid & 63;
  if (lane == 0) ssum[w] = part;
  __syncthreads();
  int base = r * 4;
  double sum = (ssum[base] + ssum[base + 1]) + (ssum[base + 2] + ssum[base + 3]);
  double inv = 1.0 / sum;
  att[i * NN + j0] = m0 ? (float)(e0 * inv) : 0.f;
  att[i * NN + j1] = m1 ? (float)(e1 * inv) : 0.f;
}

// ---------- K4: Hn = att @ H ----------
// 512 threads, 2 rows per block; j-dim split 4-way per thread, float4 H loads.
__global__ __launch_bounds__(512) void attmm_k(const float* __restrict__ att, const float* __restrict__ H,
                        float* __restrict__ Hn){
  int b = blockIdx.x, tid = threadIdx.x;
  int i0 = 2 * b;
  __shared__ float as[2][NN];
  as[0][tid] = att[i0 * NN + tid];
  as[1][tid] = att[(i0 + 1) * NN + tid];
  __syncthreads();
  int q  = tid & 63;          // col quad (cols 4q..4q+3)
  int r  = (tid >> 6) & 1;    // row
  int ks = tid >> 7;          // j segment 0..3
  const float4* H4 = (const float4*)H;     // H4[j*64 + q]
  const float* ar = as[r];
  float4 acc = {0,0,0,0};
  int jb = ks * 128;
  #pragma unroll 8
  for (int j = jb; j < jb + 128; j++){
    float a = ar[j];
    float4 h = H4[j * 64 + q];
    acc.x = fmaf(a, h.x, acc.x); acc.y = fmaf(a, h.y, acc.y);
    acc.z = fmaf(a, h.z, acc.z); acc.w = fmaf(a, h.w, acc.w);
  }
  __shared__ float4 part[2][4][64];
  part[r][ks][q] = acc;
  __syncthreads();
  if (tid < 128){
    int rr = tid >> 6, qq = tid & 63;
    float4 p0 = part[rr][0][qq], p1 = part[rr][1][qq];
    float4 p2 = part[rr][2][qq], p3 = part[rr][3][qq];
    float4 o;
    o.x = (p0.x + p1.x) + (p2.x + p3.x);
    o.y = (p0.y + p1.y) + (p2.y + p3.y);
    o.z = (p0.z + p1.z) + (p2.z + p3.z);
    o.w = (p0.w + p1.w) + (p2.w + p3.w);
    ((float4*)(Hn + (i0 + rr) * DD))[qq] = o;
  }
}

extern "C" void kernel_launch(void* const* d_in, const int* in_sizes, int n_in,
                              void* d_out, int out_size, void* d_ws, size_t ws_size,
                              hipStream_t stream){
  const float* H_euc = (const float*)d_in[0];
  const float* W     = (const float*)d_in[1];
  const int*   A     = (const int*)d_in[2];
  float* out = (float*)d_out;

  float* Hf  = (float*)d_ws;         // N*D
  float* Hn  = Hf + NN * DD;         // N*D
  float* Wh  = Hn + NN * DD;         // N*D
  float* att = Wh + NN * DD;         // N*N
  double* r2 = (double*)(att + NN * NN);  // N  (offset is 8B-aligned)

  expmap_k<<<NN, DD, 0, stream>>>(H_euc, Hf);

  // layer 0
  matvec_k<<<NN, DD, 0, stream>>>(Hf, W, Wh, r2);
  scores_k<<<NN / 2, 2 * DD, 0, stream>>>(Wh, r2, A, att);
  attmm_k <<<NN / 2, 2 * DD, 0, stream>>>(att, Hf, Hn);
  // layer 1
  matvec_k<<<NN, DD, 0, stream>>>(Hn, W + DD * DD, Wh, r2);
  scores_k<<<NN / 2, 2 * DD, 0, stream>>>(Wh, r2, A, att);
  attmm_k <<<NN / 2, 2 * DD, 0, stream>>>(att, Hn, out);
}

// Round 2
// 85.240 us; speedup vs baseline: 1.5025x; 1.5025x over previous
//
#include <hip/hip_runtime.h>
#include <math.h>

#define NN 512
#define DD 256

// ---------- dual-channel f64 block reduction (256 threads = 4 waves) ----------
__device__ __forceinline__ void wred_sum2(double& a, double& b){
  #pragma unroll
  for (int o = 32; o > 0; o >>= 1){
    a += __shfl_down(a, o);
    b += __shfl_down(b, o);
  }
}
__device__ void bred_sum2(double& a, double& b){
  __shared__ double sa[4], sb[4]; __shared__ double ra, rb;
  int lane = threadIdx.x & 63, w = threadIdx.x >> 6;
  wred_sum2(a, b);
  __syncthreads();
  if (lane == 0){ sa[w] = a; sb[w] = b; }
  __syncthreads();
  if (threadIdx.x == 0){
    ra = (sa[0] + sa[1]) + (sa[2] + sa[3]);
    rb = (sb[0] + sb[1]) + (sb[2] + sb[3]);
  }
  __syncthreads();
  a = ra; b = rb;
}

__device__ __forceinline__ double artanh_clip(double x){
  const double lim = 1.0 - 1e-5;           // BALL_EPS
  if (x >  lim) x =  lim;
  if (x < -lim) x = -lim;
  return 0.5 * log((1.0 + x) / (1.0 - x));
}

// ---------- K1: mobius_matvec for 2 rows/block; layer-0 variant fuses expmap ----------
// MODE 0: Hin = u (euclidean); expmap computed in-block, ||h|| = tanh(||u||) closed form.
// MODE 1: Hin = H; ||H row||^2 supplied via hn2 (computed by previous fused_k).
template<int MODE>
__global__ __launch_bounds__(256) void matvec_k(
    const float* __restrict__ Hin, const float* __restrict__ W,
    const double* __restrict__ hn2, float* __restrict__ Hf,
    float* __restrict__ Wh, double* __restrict__ r2){
  int b = blockIdx.x, t = threadIdx.x;
  int i0 = 2 * b, i1 = i0 + 1;
  __shared__ float h0s[DD], h1s[DD];
  float h0, h1;
  double xn0, xn1;
  if (MODE == 0){
    float u0 = Hin[i0 * DD + t], u1 = Hin[i1 * DD + t];
    double n0 = (double)u0 * (double)u0, n1 = (double)u1 * (double)u1;
    bred_sum2(n0, n1);
    n0 = sqrt(n0); if (n0 < 1e-15) n0 = 1e-15;
    n1 = sqrt(n1); if (n1 < 1e-15) n1 = 1e-15;
    double t0 = tanh(n0), t1 = tanh(n1);
    h0 = (float)(t0 / n0 * (double)u0);
    h1 = (float)(t1 / n1 * (double)u1);
    Hf[i0 * DD + t] = h0; Hf[i1 * DD + t] = h1;
    xn0 = t0; xn1 = t1;                    // ||expmap0(u)|| = tanh(||u||)
    if (xn0 < 1e-15) xn0 = 1e-15;
    if (xn1 < 1e-15) xn1 = 1e-15;
  } else {
    h0 = Hin[i0 * DD + t]; h1 = Hin[i1 * DD + t];
    xn0 = sqrt(hn2[i0]); if (xn0 < 1e-15) xn0 = 1e-15;
    xn1 = sqrt(hn2[i1]); if (xn1 < 1e-15) xn1 = 1e-15;
  }
  h0s[t] = h0; h1s[t] = h1;
  __syncthreads();
  const float4* Wt = (const float4*)(W + t * DD);   // Mx[t] = sum_k H[k]*W[t][k]
  const float4* r0 = (const float4*)h0s;
  const float4* r1 = (const float4*)h1s;
  float4 A0 = {0,0,0,0}, A1 = {0,0,0,0};
  #pragma unroll 8
  for (int k = 0; k < DD / 4; k++){
    float4 w = Wt[k], x0 = r0[k], x1 = r1[k];
    A0.x = fmaf(x0.x, w.x, A0.x); A0.y = fmaf(x0.y, w.y, A0.y);
    A0.z = fmaf(x0.z, w.z, A0.z); A0.w = fmaf(x0.w, w.w, A0.w);
    A1.x = fmaf(x1.x, w.x, A1.x); A1.y = fmaf(x1.y, w.y, A1.y);
    A1.z = fmaf(x1.z, w.z, A1.z); A1.w = fmaf(x1.w, w.w, A1.w);
  }
  float mx0 = (A0.x + A0.y) + (A0.z + A0.w);
  float mx1 = (A1.x + A1.y) + (A1.z + A1.w);
  double m0 = (double)mx0 * (double)mx0, m1 = (double)mx1 * (double)mx1;
  bred_sum2(m0, m1);
  double mn0 = sqrt(m0); if (mn0 < 1e-15) mn0 = 1e-15;
  double mn1 = sqrt(m1); if (mn1 < 1e-15) mn1 = 1e-15;
  double th0 = tanh(mn0 / xn0 * artanh_clip(xn0));
  double th1 = tanh(mn1 / xn1 * artanh_clip(xn1));
  Wh[i0 * DD + t] = (float)(mx0 * (th0 / mn0));
  Wh[i1 * DD + t] = (float)(mx1 * (th1 / mn1));
  if (t == 0){ r2[i0] = th0 * th0; r2[i1] = th1 * th1; }
}

// ---------- K2: fused Gram-tile + score (f64) + softmax + att@H ----------
// 256 threads, block b owns rows i0=2b, i1=2b+1. att lives only in LDS.
// Fixed-shift softmax: scores in [0,150) => exp(v-150) has exact ratios, no max-reduce.
// Also emits hn2[i] = ||Hn row i||^2 for the next layer's matvec.
__global__ __launch_bounds__(256) void fused_k(
    const float* __restrict__ Wh, const double* __restrict__ r2,
    const int* __restrict__ A, const float* __restrict__ H,
    float* __restrict__ Hn, double* __restrict__ hn2){
  int b = blockIdx.x, t = threadIdx.x;
  int i0 = 2 * b, i1 = i0 + 1;
  __shared__ float x0s[DD], x1s[DD];
  __shared__ float a0s[NN], a1s[NN];
  x0s[t] = Wh[i0 * DD + t];
  x1s[t] = Wh[i1 * DD + t];
  __syncthreads();
  int j0 = t, j1 = t + DD;
  const float4* wj0 = (const float4*)(Wh + j0 * DD);
  const float4* wj1 = (const float4*)(Wh + j1 * DD);
  const float4* x0  = (const float4*)x0s;
  const float4* x1  = (const float4*)x1s;
  // 4 dots, 16 independent FMA chains (best measured shape, round 0)
  float4 s00 = {0,0,0,0}, s01 = {0,0,0,0}, s10 = {0,0,0,0}, s11 = {0,0,0,0};
  #pragma unroll 4
  for (int k = 0; k < DD / 4; k++){
    float4 a = wj0[k], c = wj1[k], p = x0[k], q = x1[k];
    s00.x = fmaf(p.x, a.x, s00.x); s00.y = fmaf(p.y, a.y, s00.y);
    s00.z = fmaf(p.z, a.z, s00.z); s00.w = fmaf(p.w, a.w, s00.w);
    s01.x = fmaf(p.x, c.x, s01.x); s01.y = fmaf(p.y, c.y, s01.y);
    s01.z = fmaf(p.z, c.z, s01.z); s01.w = fmaf(p.w, c.w, s01.w);
    s10.x = fmaf(q.x, a.x, s10.x); s10.y = fmaf(q.y, a.y, s10.y);
    s10.z = fmaf(q.z, a.z, s10.z); s10.w = fmaf(q.w, a.w, s10.w);
    s11.x = fmaf(q.x, c.x, s11.x); s11.y = fmaf(q.y, c.y, s11.y);
    s11.z = fmaf(q.z, c.z, s11.z); s11.w = fmaf(q.w, c.w, s11.w);
  }
  double d00 = (double)((s00.x + s00.y) + (s00.z + s00.w));
  double d01 = (double)((s01.x + s01.y) + (s01.z + s01.w));
  double d10 = (double)((s10.x + s10.y) + (s10.z + s10.w));
  double d11 = (double)((s11.x + s11.y) + (s11.z + s11.w));

  double X0 = r2[i0], X1 = r2[i1];
  double Y0 = r2[j0], Y1 = r2[j1];

  auto score = [&](double dot, double X2, double Y2, int ii, int jj) -> double {
    if (ii == jj) return 0.0;              // exact: mobius_add(-x,x)=0
    double xy = -dot;
    double a  = 1.0 + 2.0 * xy + Y2;
    double bb = 1.0 - X2;
    double den = 1.0 + 2.0 * xy + X2 * Y2;
    if (den < 1e-15) den = 1e-15;
    double nn = a * a * X2 + 2.0 * a * bb * xy + bb * bb * Y2;
    if (nn < 0.0) nn = 0.0;
    double s = sqrt(nn);
    double smax = den * (1.0 - 1e-5);      // artanh arg clip at 1-1e-5
    if (s > smax) s = smax;
    double d = log((den + s) / (den - s)); // = 2*artanh(s/den), one div
    return d * d;
  };

  int m00 = A[i0 * NN + j0], m01 = A[i0 * NN + j1];
  int m10 = A[i1 * NN + j0], m11 = A[i1 * NN + j1];
  double e00 = 0.0, e01 = 0.0, e10 = 0.0, e11 = 0.0;
  if (m00) e00 = exp(score(d00, X0, Y0, i0, j0) - 150.0);
  if (m01) e01 = exp(score(d01, X0, Y1, i0, j1) - 150.0);
  if (m10) e10 = exp(score(d10, X1, Y0, i1, j0) - 150.0);
  if (m11) e11 = exp(score(d11, X1, Y1, i1, j1) - 150.0);

  double sm0 = e00 + e01, sm1 = e10 + e11;
  bred_sum2(sm0, sm1);
  double inv0 = 1.0 / sm0, inv1 = 1.0 / sm1;
  a0s[j0] = (float)(e00 * inv0); a0s[j1] = (float)(e01 * inv0);
  a1s[j0] = (float)(e10 * inv1); a1s[j1] = (float)(e11 * inv1);
  __syncthreads();

  // ---- att @ H : j split 4-way, float4 H loads (16B/lane) ----
  int q  = t & 63;            // output col quad (cols 4q..4q+3)
  int sg = t >> 6;            // j segment 0..3
  const float4* H4 = (const float4*)H;     // H4[j*64 + q]
  float4 c0 = {0,0,0,0}, c1 = {0,0,0,0};
  int jb = sg * 128;
  #pragma unroll 8
  for (int jj = 0; jj < 128; jj++){
    int j = jb + jj;
    float a0 = a0s[j], a1 = a1s[j];        // wave-uniform -> LDS broadcast
    float4 h = H4[j * 64 + q];
    c0.x = fmaf(a0, h.x, c0.x); c0.y = fmaf(a0, h.y, c0.y);
    c0.z = fmaf(a0, h.z, c0.z); c0.w = fmaf(a0, h.w, c0.w);
    c1.x = fmaf(a1, h.x, c1.x); c1.y = fmaf(a1, h.y, c1.y);
    c1.z = fmaf(a1, h.z, c1.z); c1.w = fmaf(a1, h.w, c1.w);
  }
  __shared__ float4 part[2][4][64];
  part[0][sg][q] = c0;
  part[1][sg][q] = c1;
  __syncthreads();
  if (t < 128){
    int rr = t >> 6, qq = t & 63;          // row rr handled by wave rr
    float4 p0 = part[rr][0][qq], p1 = part[rr][1][qq];
    float4 p2 = part[rr][2][qq], p3 = part[rr][3][qq];
    float4 o;
    o.x = (p0.x + p1.x) + (p2.x + p3.x);
    o.y = (p0.y + p1.y) + (p2.y + p3.y);
    o.z = (p0.z + p1.z) + (p2.z + p3.z);
    o.w = (p0.w + p1.w) + (p2.w + p3.w);
    ((float4*)(Hn + (i0 + rr) * DD))[qq] = o;
    // ||Hn row||^2 for next layer's matvec (wave-local reduce, rows==waves)
    double s = (double)o.x * o.x + (double)o.y * o.y
             + (double)o.z * o.z + (double)o.w * o.w;
    #pragma unroll
    for (int off = 32; off > 0; off >>= 1) s += __shfl_down(s, off);
    if (qq == 0) hn2[i0 + rr] = s;
  }
}

extern "C" void kernel_launch(void* const* d_in, const int* in_sizes, int n_in,
                              void* d_out, int out_size, void* d_ws, size_t ws_size,
                              hipStream_t stream){
  const float* H_euc = (const float*)d_in[0];
  const float* W     = (const float*)d_in[1];
  const int*   A     = (const int*)d_in[2];
  float* out = (float*)d_out;

  float* Hf  = (float*)d_ws;               // N*D
  float* Hn  = Hf + NN * DD;               // N*D
  float* Wh  = Hn + NN * DD;               // N*D
  double* r2  = (double*)(Wh + NN * DD);   // N   (3*512KB offset, 8B aligned)
  double* hn2 = r2 + NN;                   // N

  // layer 0 (expmap fused into matvec)
  matvec_k<0><<<NN / 2, DD, 0, stream>>>(H_euc, W, nullptr, Hf, Wh, r2);
  fused_k   <<<NN / 2, DD, 0, stream>>>(Wh, r2, A, Hf, Hn, hn2);
  // layer 1
  matvec_k<1><<<NN / 2, DD, 0, stream>>>(Hn, W + DD * DD, hn2, nullptr, Wh, r2);
  fused_k   <<<NN / 2, DD, 0, stream>>>(Wh, r2, A, Hn, out, hn2);
}

// Round 3
// 61.141 us; speedup vs baseline: 2.0947x; 1.3942x over previous
//
#include <hip/hip_runtime.h>
#include <math.h>

#define NN 512
#define DD 256

// ---------- dual-channel f64 block reduction (256 threads = 4 waves) ----------
__device__ __forceinline__ void wred_sum2(double& a, double& b){
  #pragma unroll
  for (int o = 32; o > 0; o >>= 1){
    a += __shfl_down(a, o);
    b += __shfl_down(b, o);
  }
}
__device__ void bred_sum2(double& a, double& b){
  __shared__ double sa[4], sb[4]; __shared__ double ra, rb;
  int lane = threadIdx.x & 63, w = threadIdx.x >> 6;
  wred_sum2(a, b);
  __syncthreads();
  if (lane == 0){ sa[w] = a; sb[w] = b; }
  __syncthreads();
  if (threadIdx.x == 0){
    ra = (sa[0] + sa[1]) + (sa[2] + sa[3]);
    rb = (sb[0] + sb[1]) + (sb[2] + sb[3]);
  }
  __syncthreads();
  a = ra; b = rb;
}

__device__ __forceinline__ double artanh_clip(double x){
  const double lim = 1.0 - 1e-5;           // BALL_EPS
  if (x >  lim) x =  lim;
  if (x < -lim) x = -lim;
  return 0.5 * log((1.0 + x) / (1.0 - x));
}

// ---------- K1: mobius_matvec, 2 rows/block; writes Wh (row-major) AND WhT ----------
// MODE 0: Hin = u (euclidean); expmap fused, ||h|| = tanh(||u||) closed form.
// MODE 1: Hin = H; ||H row||^2 supplied via hn2 (from previous fused_k).
template<int MODE>
__global__ __launch_bounds__(256) void matvec_k(
    const float* __restrict__ Hin, const float* __restrict__ W,
    const double* __restrict__ hn2, float* __restrict__ Hf,
    float* __restrict__ Wh, float* __restrict__ WhT, double* __restrict__ r2){
  int b = blockIdx.x, t = threadIdx.x;
  int i0 = 2 * b, i1 = i0 + 1;
  __shared__ float h0s[DD], h1s[DD];
  float h0, h1;
  double xn0, xn1;
  if (MODE == 0){
    float u0 = Hin[i0 * DD + t], u1 = Hin[i1 * DD + t];
    double n0 = (double)u0 * (double)u0, n1 = (double)u1 * (double)u1;
    bred_sum2(n0, n1);
    n0 = sqrt(n0); if (n0 < 1e-15) n0 = 1e-15;
    n1 = sqrt(n1); if (n1 < 1e-15) n1 = 1e-15;
    double t0 = tanh(n0), t1 = tanh(n1);
    h0 = (float)(t0 / n0 * (double)u0);
    h1 = (float)(t1 / n1 * (double)u1);
    Hf[i0 * DD + t] = h0; Hf[i1 * DD + t] = h1;
    xn0 = t0; xn1 = t1;                    // ||expmap0(u)|| = tanh(||u||)
    if (xn0 < 1e-15) xn0 = 1e-15;
    if (xn1 < 1e-15) xn1 = 1e-15;
  } else {
    h0 = Hin[i0 * DD + t]; h1 = Hin[i1 * DD + t];
    xn0 = sqrt(hn2[i0]); if (xn0 < 1e-15) xn0 = 1e-15;
    xn1 = sqrt(hn2[i1]); if (xn1 < 1e-15) xn1 = 1e-15;
  }
  h0s[t] = h0; h1s[t] = h1;
  __syncthreads();
  const float4* Wt = (const float4*)(W + t * DD);   // Mx[t] = sum_k H[k]*W[t][k]
  const float4* r0 = (const float4*)h0s;
  const float4* r1 = (const float4*)h1s;
  float4 A0 = {0,0,0,0}, A1 = {0,0,0,0};
  #pragma unroll 8
  for (int k = 0; k < DD / 4; k++){
    float4 w = Wt[k], x0 = r0[k], x1 = r1[k];
    A0.x = fmaf(x0.x, w.x, A0.x); A0.y = fmaf(x0.y, w.y, A0.y);
    A0.z = fmaf(x0.z, w.z, A0.z); A0.w = fmaf(x0.w, w.w, A0.w);
    A1.x = fmaf(x1.x, w.x, A1.x); A1.y = fmaf(x1.y, w.y, A1.y);
    A1.z = fmaf(x1.z, w.z, A1.z); A1.w = fmaf(x1.w, w.w, A1.w);
  }
  float mx0 = (A0.x + A0.y) + (A0.z + A0.w);
  float mx1 = (A1.x + A1.y) + (A1.z + A1.w);
  double m0 = (double)mx0 * (double)mx0, m1 = (double)mx1 * (double)mx1;
  bred_sum2(m0, m1);
  double mn0 = sqrt(m0); if (mn0 < 1e-15) mn0 = 1e-15;
  double mn1 = sqrt(m1); if (mn1 < 1e-15) mn1 = 1e-15;
  double th0 = tanh(mn0 / xn0 * artanh_clip(xn0));
  double th1 = tanh(mn1 / xn1 * artanh_clip(xn1));
  float w0 = (float)(mx0 * (th0 / mn0));
  float w1 = (float)(mx1 * (th1 / mn1));
  Wh[i0 * DD + t] = w0;  Wh[i1 * DD + t] = w1;
  WhT[t * NN + i0] = w0; WhT[t * NN + i1] = w1;   // transposed copy for streamed Gram
  if (t == 0){ r2[i0] = th0 * th0; r2[i1] = th1 * th1; }
}

// ---------- K2: fused Gram + score (f64) + softmax + att@H, 512 threads ----------
// Block b owns rows i0=2b, i1=2b+1; 8 waves/block = 2 waves/SIMD.
// Phase A: streamed Gram from WhT (coalesced float4), 4-way k-split + LDS combine.
// Phase B: 2 scores/thread (row r = tid>>8, cols j2, j2+256), fixed-shift softmax.
// Phase C: att@H, 8-way j-split, float4 H loads; emits hn2 for next layer.
__global__ __launch_bounds__(512) void fused_k(
    const float* __restrict__ Wh, const float* __restrict__ WhT,
    const double* __restrict__ r2, const int* __restrict__ A,
    const float* __restrict__ H, float* __restrict__ Hn, double* __restrict__ hn2){
  int b = blockIdx.x, tid = threadIdx.x;
  int i0 = 2 * b;
  __shared__ float xs[2 * DD];          // Wh rows i0,i1 (contiguous)
  __shared__ float a_s[2][NN];          // attention rows
  __shared__ float4 parts[4 * 128 * 2]; // phase A: [ks][jq][row]; phase C: [r][sg][q]
  __shared__ double ssum[8];

  xs[tid] = Wh[i0 * DD + tid];          // 512 floats = both rows
  __syncthreads();

  // ---- Phase A: Gram partials, fully coalesced stream of WhT ----
  {
    int ks = tid >> 7, jq = tid & 127;  // k-segment (64 dims), column-quad
    const float4* WT4 = (const float4*)WhT;      // [k*128 + jq]
    const float* x0 = xs, * x1 = xs + DD;
    float4 p0 = {0,0,0,0}, p1 = {0,0,0,0};
    int k0 = ks * 64;
    #pragma unroll 8
    for (int kk = 0; kk < 64; kk++){
      int k = k0 + kk;
      float4 w = WT4[k * 128 + jq];
      float a0v = x0[k], a1v = x1[k];   // wave-uniform -> LDS broadcast
      p0.x = fmaf(a0v, w.x, p0.x); p0.y = fmaf(a0v, w.y, p0.y);
      p0.z = fmaf(a0v, w.z, p0.z); p0.w = fmaf(a0v, w.w, p0.w);
      p1.x = fmaf(a1v, w.x, p1.x); p1.y = fmaf(a1v, w.y, p1.y);
      p1.z = fmaf(a1v, w.z, p1.z); p1.w = fmaf(a1v, w.w, p1.w);
    }
    parts[(ks * 128 + jq) * 2 + 0] = p0;
    parts[(ks * 128 + jq) * 2 + 1] = p1;
  }
  __syncthreads();

  // ---- Phase B: scores + fixed-shift softmax ----
  int r = tid >> 8, j2 = tid & 255;     // waves 0-3: row i0, waves 4-7: row i1
  int i = i0 + r;
  double X2 = r2[i];
  const float* pf = (const float*)parts;          // ks stride = 1024 floats

  auto dsum = [&](int j) -> double {
    int base = (((j >> 2) * 2 + r) << 2) + (j & 3);
    return ((double)pf[base] + (double)pf[base + 1024])
         + ((double)pf[base + 2048] + (double)pf[base + 3072]);
  };
  double d0 = dsum(j2), d1 = dsum(j2 + 256);

  auto score = [&](double dot, double Y2, int jj) -> double {
    if (i == jj) return 0.0;            // exact: mobius_add(-x,x)=0
    double xy = -dot;
    double a  = 1.0 + 2.0 * xy + Y2;
    double bb = 1.0 - X2;
    double den = 1.0 + 2.0 * xy + X2 * Y2;
    if (den < 1e-15) den = 1e-15;
    double nn = a * a * X2 + 2.0 * a * bb * xy + bb * bb * Y2;
    if (nn < 0.0) nn = 0.0;
    double s = sqrt(nn);
    double smax = den * (1.0 - 1e-5);   // artanh arg clip at 1-1e-5
    if (s > smax) s = smax;
    double d = log((den + s) / (den - s)); // = 2*artanh(s/den), one div
    return d * d;
  };

  double Y0 = r2[j2], Y1 = r2[j2 + 256];
  int m0 = A[i * NN + j2], m1 = A[i * NN + j2 + 256];
  double e0 = 0.0, e1 = 0.0;
  if (m0) e0 = exp(score(d0, Y0, j2) - 150.0);         // scores in [0,150)
  if (m1) e1 = exp(score(d1, Y1, j2 + 256) - 150.0);

  double part = e0 + e1;
  #pragma unroll
  for (int o = 32; o > 0; o >>= 1) part += __shfl_down(part, o);
  int w = tid >> 6, lane = tid & 63;
  if (lane == 0) ssum[w] = part;
  __syncthreads();
  int base4 = r * 4;
  double sum = (ssum[base4] + ssum[base4 + 1]) + (ssum[base4 + 2] + ssum[base4 + 3]);
  double inv = 1.0 / sum;
  a_s[r][j2]       = m0 ? (float)(e0 * inv) : 0.f;
  a_s[r][j2 + 256] = m1 ? (float)(e1 * inv) : 0.f;
  __syncthreads();

  // ---- Phase C: att @ H, 8-way j-split, float4 loads ----
  {
    int sg = tid >> 6, q = tid & 63;    // j-segment (64 each), output col-quad
    const float4* H4 = (const float4*)H;          // [j*64 + q]
    float4 c0 = {0,0,0,0}, c1 = {0,0,0,0};
    int jb = sg * 64;
    #pragma unroll 8
    for (int jj = 0; jj < 64; jj++){
      int j = jb + jj;
      float a0 = a_s[0][j], a1 = a_s[1][j];       // wave-uniform broadcast
      float4 h = H4[j * 64 + q];
      c0.x = fmaf(a0, h.x, c0.x); c0.y = fmaf(a0, h.y, c0.y);
      c0.z = fmaf(a0, h.z, c0.z); c0.w = fmaf(a0, h.w, c0.w);
      c1.x = fmaf(a1, h.x, c1.x); c1.y = fmaf(a1, h.y, c1.y);
      c1.z = fmaf(a1, h.z, c1.z); c1.w = fmaf(a1, h.w, c1.w);
    }
    float4* part2 = parts;              // reuse: [r*512 + sg*64 + q]
    part2[sg * 64 + q]       = c0;
    part2[512 + sg * 64 + q] = c1;
  }
  __syncthreads();
  if (tid < 128){
    int rr = tid >> 6, qq = tid & 63;   // wave 0 -> row i0, wave 1 -> row i1
    const float4* part2 = parts;
    float4 p[8];
    #pragma unroll
    for (int s8 = 0; s8 < 8; s8++) p[s8] = part2[rr * 512 + s8 * 64 + qq];
    float4 o;
    o.x = ((p[0].x + p[1].x) + (p[2].x + p[3].x)) + ((p[4].x + p[5].x) + (p[6].x + p[7].x));
    o.y = ((p[0].y + p[1].y) + (p[2].y + p[3].y)) + ((p[4].y + p[5].y) + (p[6].y + p[7].y));
    o.z = ((p[0].z + p[1].z) + (p[2].z + p[3].z)) + ((p[4].z + p[5].z) + (p[6].z + p[7].z));
    o.w = ((p[0].w + p[1].w) + (p[2].w + p[3].w)) + ((p[4].w + p[5].w) + (p[6].w + p[7].w));
    ((float4*)(Hn + (i0 + rr) * DD))[qq] = o;
    // ||Hn row||^2 for next layer's matvec (row rr owned by wave rr)
    double s = (double)o.x * o.x + (double)o.y * o.y
             + (double)o.z * o.z + (double)o.w * o.w;
    #pragma unroll
    for (int off = 32; off > 0; off >>= 1) s += __shfl_down(s, off);
    if (qq == 0) hn2[i0 + rr] = s;
  }
}

extern "C" void kernel_launch(void* const* d_in, const int* in_sizes, int n_in,
                              void* d_out, int out_size, void* d_ws, size_t ws_size,
                              hipStream_t stream){
  const float* H_euc = (const float*)d_in[0];
  const float* W     = (const float*)d_in[1];
  const int*   A     = (const int*)d_in[2];
  float* out = (float*)d_out;

  float* Hf  = (float*)d_ws;               // N*D
  float* Hn  = Hf + NN * DD;               // N*D
  float* Wh  = Hn + NN * DD;               // N*D
  float* WhT = Wh + NN * DD;               // D*N (transposed Wh)
  double* r2  = (double*)(WhT + NN * DD);  // N
  double* hn2 = r2 + NN;                   // N

  // layer 0 (expmap fused into matvec)
  matvec_k<0><<<NN / 2, DD, 0, stream>>>(H_euc, W, nullptr, Hf, Wh, WhT, r2);
  fused_k    <<<NN / 2, 2 * DD, 0, stream>>>(Wh, WhT, r2, A, Hf, Hn, hn2);
  // layer 1
  matvec_k<1><<<NN / 2, DD, 0, stream>>>(Hn, W + DD * DD, hn2, nullptr, Wh, WhT, r2);
  fused_k    <<<NN / 2, 2 * DD, 0, stream>>>(Wh, WhT, r2, A, Hn, out, hn2);
}

// Round 4
// 52.921 us; speedup vs baseline: 2.4201x; 1.1553x over previous
//
#include <hip/hip_runtime.h>
#include <math.h>

#define NN 512
#define DD 256

// ---------- dual-channel f64 block reduction (256 threads = 4 waves) ----------
__device__ __forceinline__ void wred_sum2(double& a, double& b){
  #pragma unroll
  for (int o = 32; o > 0; o >>= 1){
    a += __shfl_down(a, o);
    b += __shfl_down(b, o);
  }
}
__device__ void bred_sum2(double& a, double& b){
  __shared__ double sa[4], sb[4]; __shared__ double ra, rb;
  int lane = threadIdx.x & 63, w = threadIdx.x >> 6;
  wred_sum2(a, b);
  __syncthreads();
  if (lane == 0){ sa[w] = a; sb[w] = b; }
  __syncthreads();
  if (threadIdx.x == 0){
    ra = (sa[0] + sa[1]) + (sa[2] + sa[3]);
    rb = (sb[0] + sb[1]) + (sb[2] + sb[3]);
  }
  __syncthreads();
  a = ra; b = rb;
}

__device__ __forceinline__ double artanh_clip(double x){
  const double lim = 1.0 - 1e-5;           // BALL_EPS
  if (x >  lim) x =  lim;
  if (x < -lim) x = -lim;
  return 0.5 * log((1.0 + x) / (1.0 - x));
}

// ---------- K0: expmap + mobius_matvec layer 0 (2 rows/block) ----------
// Blocks 0..15 additionally produce W1T (tiled LDS transpose of layer-1 W)
// for the coalesced tail-matvec inside fused_k<false>.
__global__ __launch_bounds__(256) void matvec0_k(
    const float* __restrict__ Hin, const float* __restrict__ W,
    const float* __restrict__ W1, float* __restrict__ W1T,
    float* __restrict__ Hf, float* __restrict__ Wh, float* __restrict__ WhT,
    double* __restrict__ r2){
  __shared__ float h0s[DD], h1s[DD];
  __shared__ float tile[64][65];
  int b = blockIdx.x, t = threadIdx.x;
  int i0 = 2 * b, i1 = i0 + 1;
  float u0 = Hin[i0 * DD + t], u1 = Hin[i1 * DD + t];
  double n0 = (double)u0 * (double)u0, n1 = (double)u1 * (double)u1;
  bred_sum2(n0, n1);
  n0 = sqrt(n0); if (n0 < 1e-15) n0 = 1e-15;
  n1 = sqrt(n1); if (n1 < 1e-15) n1 = 1e-15;
  double t0 = tanh(n0), t1 = tanh(n1);
  float h0 = (float)(t0 / n0 * (double)u0);
  float h1 = (float)(t1 / n1 * (double)u1);
  Hf[i0 * DD + t] = h0; Hf[i1 * DD + t] = h1;
  double xn0 = t0 < 1e-15 ? 1e-15 : t0;    // ||expmap0(u)|| = tanh(||u||)
  double xn1 = t1 < 1e-15 ? 1e-15 : t1;
  h0s[t] = h0; h1s[t] = h1;
  __syncthreads();
  const float4* Wt = (const float4*)(W + t * DD);   // Mx[t] = sum_k H[k]*W[t][k]
  const float4* r0 = (const float4*)h0s;
  const float4* r1 = (const float4*)h1s;
  float4 A0 = {0,0,0,0}, A1 = {0,0,0,0};
  #pragma unroll 8
  for (int k = 0; k < DD / 4; k++){
    float4 w = Wt[k], x0 = r0[k], x1 = r1[k];
    A0.x = fmaf(x0.x, w.x, A0.x); A0.y = fmaf(x0.y, w.y, A0.y);
    A0.z = fmaf(x0.z, w.z, A0.z); A0.w = fmaf(x0.w, w.w, A0.w);
    A1.x = fmaf(x1.x, w.x, A1.x); A1.y = fmaf(x1.y, w.y, A1.y);
    A1.z = fmaf(x1.z, w.z, A1.z); A1.w = fmaf(x1.w, w.w, A1.w);
  }
  float mx0 = (A0.x + A0.y) + (A0.z + A0.w);
  float mx1 = (A1.x + A1.y) + (A1.z + A1.w);
  double m0 = (double)mx0 * (double)mx0, m1 = (double)mx1 * (double)mx1;
  bred_sum2(m0, m1);
  double mn0 = sqrt(m0); if (mn0 < 1e-15) mn0 = 1e-15;
  double mn1 = sqrt(m1); if (mn1 < 1e-15) mn1 = 1e-15;
  double th0 = tanh(mn0 / xn0 * artanh_clip(xn0));
  double th1 = tanh(mn1 / xn1 * artanh_clip(xn1));
  float w0 = (float)(mx0 * (th0 / mn0));
  float w1 = (float)(mx1 * (th1 / mn1));
  Wh[i0 * DD + t] = w0;  Wh[i1 * DD + t] = w1;
  WhT[t * NN + i0] = w0; WhT[t * NN + i1] = w1;
  if (t == 0){ r2[i0] = th0 * th0; r2[i1] = th1 * th1; }

  // ---- W1 transpose: blocks 0..15 each do one 64x64 tile (block-uniform branch) ----
  if (b < 16){
    int tr = b >> 2, tc = b & 3;
    int tx = t & 63, ty4 = t >> 6;           // 4 rows per pass
    #pragma unroll
    for (int yy = 0; yy < 64; yy += 4)
      tile[yy + ty4][tx] = W1[(tr * 64 + yy + ty4) * DD + tc * 64 + tx];
    __syncthreads();
    #pragma unroll
    for (int yy = 0; yy < 64; yy += 4)
      W1T[(tc * 64 + yy + ty4) * DD + tr * 64 + tx] = tile[tx][yy + ty4];
  }
}

// ---------- fused: Gram + score(f64) + softmax + att@H (+ next-layer matvec tail) ----------
// 512 threads, block b owns rows i0=2b, i1=2b+1.
// A: Gram partials from WhT (coalesced float4, 4-way k-split, 16 loads in flight).
// B: 2 scores/thread, fixed-shift softmax (scores in [0,150) -> exp(v-150), no max-reduce).
// C: att@H with 8-way j-split; first 8 rows register-prefetched under phase B.
// Tail (!LAST): mobius_matvec of this block's 2 Hn rows via W1T (coalesced), writes
//               Whn/WhTn/r2n for the next fused_k. Kills a launch + Hn round-trip.
template<bool LAST>
__global__ __launch_bounds__(512) void fused_k(
    const float* __restrict__ Wh, const float* __restrict__ WhT,
    const double* __restrict__ r2, const int* __restrict__ A,
    const float* __restrict__ H, const float* __restrict__ WT2,
    float* __restrict__ Hn, float* __restrict__ Whn,
    float* __restrict__ WhTn, double* __restrict__ r2n){
  int b = blockIdx.x, tid = threadIdx.x;
  int i0 = 2 * b;
  __shared__ float xs[2 * DD];
  __shared__ float a_s[2][NN];
  __shared__ float4 parts[1024];        // 16KB, reused by phases A-combine, C, tail
  __shared__ double ssum[8];
  __shared__ float hn_s[2][DD];
  __shared__ double hnorm2[2];

  xs[tid] = Wh[i0 * DD + tid];
  __syncthreads();

  // ---- Phase A: Gram partials ----
  {
    int ks = tid >> 7, jq = tid & 127;  // k-segment (64 dims), column-quad
    const float4* WT4 = (const float4*)WhT;        // [k*128 + jq]
    const float4* x04 = (const float4*)xs;
    const float4* x14 = (const float4*)(xs + DD);
    float4 p0 = {0,0,0,0}, p1 = {0,0,0,0};
    int kq0 = ks * 16;
    #pragma unroll 4
    for (int kk = 0; kk < 16; kk++){
      float4 xa = x04[kq0 + kk], xb = x14[kq0 + kk];
      const float4* wp = WT4 + (kq0 + kk) * 4 * 128 + jq;
      float4 w0 = wp[0], w1 = wp[128], w2 = wp[256], w3 = wp[384];
      p0.x = fmaf(xa.x, w0.x, p0.x); p0.y = fmaf(xa.x, w0.y, p0.y);
      p0.z = fmaf(xa.x, w0.z, p0.z); p0.w = fmaf(xa.x, w0.w, p0.w);
      p0.x = fmaf(xa.y, w1.x, p0.x); p0.y = fmaf(xa.y, w1.y, p0.y);
      p0.z = fmaf(xa.y, w1.z, p0.z); p0.w = fmaf(xa.y, w1.w, p0.w);
      p0.x = fmaf(xa.z, w2.x, p0.x); p0.y = fmaf(xa.z, w2.y, p0.y);
      p0.z = fmaf(xa.z, w2.z, p0.z); p0.w = fmaf(xa.z, w2.w, p0.w);
      p0.x = fmaf(xa.w, w3.x, p0.x); p0.y = fmaf(xa.w, w3.y, p0.y);
      p0.z = fmaf(xa.w, w3.z, p0.z); p0.w = fmaf(xa.w, w3.w, p0.w);
      p1.x = fmaf(xb.x, w0.x, p1.x); p1.y = fmaf(xb.x, w0.y, p1.y);
      p1.z = fmaf(xb.x, w0.z, p1.z); p1.w = fmaf(xb.x, w0.w, p1.w);
      p1.x = fmaf(xb.y, w1.x, p1.x); p1.y = fmaf(xb.y, w1.y, p1.y);
      p1.z = fmaf(xb.y, w1.z, p1.z); p1.w = fmaf(xb.y, w1.w, p1.w);
      p1.x = fmaf(xb.z, w2.x, p1.x); p1.y = fmaf(xb.z, w2.y, p1.y);
      p1.z = fmaf(xb.z, w2.z, p1.z); p1.w = fmaf(xb.z, w2.w, p1.w);
      p1.x = fmaf(xb.w, w3.x, p1.x); p1.y = fmaf(xb.w, w3.y, p1.y);
      p1.z = fmaf(xb.w, w3.z, p1.z); p1.w = fmaf(xb.w, w3.w, p1.w);
    }
    parts[(ks * 128 + jq) * 2 + 0] = p0;
    parts[(ks * 128 + jq) * 2 + 1] = p1;
  }
  __syncthreads();

  // ---- Phase C prefetch: first 8 rows of this thread's j-segment (hides under B) ----
  int sgC = tid >> 6, qC = tid & 63;
  const float4* H4 = (const float4*)H;
  float4 hpre[8];
  #pragma unroll
  for (int jj = 0; jj < 8; jj++) hpre[jj] = H4[(sgC * 64 + jj) * 64 + qC];

  // ---- Phase B: scores + fixed-shift softmax ----
  int r = tid >> 8, j2 = tid & 255;     // waves 0-3: row i0, waves 4-7: row i1
  int i = i0 + r;
  double X2 = r2[i];
  const float* pf = (const float*)parts;          // ks stride = 1024 floats
  auto dsum = [&](int j) -> double {
    int base = (((j >> 2) * 2 + r) << 2) + (j & 3);
    return ((double)pf[base] + (double)pf[base + 1024])
         + ((double)pf[base + 2048] + (double)pf[base + 3072]);
  };
  double d0 = dsum(j2), d1 = dsum(j2 + 256);

  auto score = [&](double dot, double Y2, int jj) -> double {
    if (i == jj) return 0.0;            // exact: mobius_add(-x,x)=0
    double xy = -dot;
    double a  = 1.0 + 2.0 * xy + Y2;
    double bb = 1.0 - X2;
    double den = 1.0 + 2.0 * xy + X2 * Y2;
    if (den < 1e-15) den = 1e-15;
    double nn = a * a * X2 + 2.0 * a * bb * xy + bb * bb * Y2;
    if (nn < 0.0) nn = 0.0;
    double s = sqrt(nn);
    double smax = den * (1.0 - 1e-5);   // artanh arg clip at 1-1e-5
    if (s > smax) s = smax;
    double d = log((den + s) / (den - s)); // = 2*artanh(s/den), one div
    return d * d;
  };

  double Y0 = r2[j2], Y1 = r2[j2 + 256];
  int m0 = A[i * NN + j2], m1 = A[i * NN + j2 + 256];
  double e0 = 0.0, e1 = 0.0;
  if (m0) e0 = exp(score(d0, Y0, j2) - 150.0);
  if (m1) e1 = exp(score(d1, Y1, j2 + 256) - 150.0);

  double part = e0 + e1;
  #pragma unroll
  for (int o = 32; o > 0; o >>= 1) part += __shfl_down(part, o);
  int w = tid >> 6, lane = tid & 63;
  if (lane == 0) ssum[w] = part;
  __syncthreads();
  int base4 = r * 4;
  double sum = (ssum[base4] + ssum[base4 + 1]) + (ssum[base4 + 2] + ssum[base4 + 3]);
  double inv = 1.0 / sum;
  a_s[r][j2]       = m0 ? (float)(e0 * inv) : 0.f;
  a_s[r][j2 + 256] = m1 ? (float)(e1 * inv) : 0.f;
  __syncthreads();

  // ---- Phase C: att @ H ----
  {
    float4 c0 = {0,0,0,0}, c1 = {0,0,0,0};
    int jb = sgC * 64;
    #pragma unroll
    for (int jj = 0; jj < 8; jj++){
      int j = jb + jj;
      float a0 = a_s[0][j], a1 = a_s[1][j];
      float4 h = hpre[jj];
      c0.x = fmaf(a0, h.x, c0.x); c0.y = fmaf(a0, h.y, c0.y);
      c0.z = fmaf(a0, h.z, c0.z); c0.w = fmaf(a0, h.w, c0.w);
      c1.x = fmaf(a1, h.x, c1.x); c1.y = fmaf(a1, h.y, c1.y);
      c1.z = fmaf(a1, h.z, c1.z); c1.w = fmaf(a1, h.w, c1.w);
    }
    #pragma unroll 8
    for (int jj = 8; jj < 64; jj++){
      int j = jb + jj;
      float a0 = a_s[0][j], a1 = a_s[1][j];
      float4 h = H4[j * 64 + qC];
      c0.x = fmaf(a0, h.x, c0.x); c0.y = fmaf(a0, h.y, c0.y);
      c0.z = fmaf(a0, h.z, c0.z); c0.w = fmaf(a0, h.w, c0.w);
      c1.x = fmaf(a1, h.x, c1.x); c1.y = fmaf(a1, h.y, c1.y);
      c1.z = fmaf(a1, h.z, c1.z); c1.w = fmaf(a1, h.w, c1.w);
    }
    parts[sgC * 64 + qC]       = c0;
    parts[512 + sgC * 64 + qC] = c1;
  }
  __syncthreads();
  if (tid < 128){
    int rr = tid >> 6, qq = tid & 63;
    float4 p[8];
    #pragma unroll
    for (int s8 = 0; s8 < 8; s8++) p[s8] = parts[rr * 512 + s8 * 64 + qq];
    float4 o;
    o.x = ((p[0].x + p[1].x) + (p[2].x + p[3].x)) + ((p[4].x + p[5].x) + (p[6].x + p[7].x));
    o.y = ((p[0].y + p[1].y) + (p[2].y + p[3].y)) + ((p[4].y + p[5].y) + (p[6].y + p[7].y));
    o.z = ((p[0].z + p[1].z) + (p[2].z + p[3].z)) + ((p[4].z + p[5].z) + (p[6].z + p[7].z));
    o.w = ((p[0].w + p[1].w) + (p[2].w + p[3].w)) + ((p[4].w + p[5].w) + (p[6].w + p[7].w));
    ((float4*)(Hn + (i0 + rr) * DD))[qq] = o;
    if (!LAST){
      ((float4*)hn_s[rr])[qq] = o;
      double s = (double)o.x * o.x + (double)o.y * o.y
               + (double)o.z * o.z + (double)o.w * o.w;
      #pragma unroll
      for (int off = 32; off > 0; off >>= 1) s += __shfl_down(s, off);
      if (qq == 0) hnorm2[rr] = s;
    }
  }
  if (LAST) return;
  __syncthreads();

  // ---- Tail: mobius_matvec for rows i0,i1 via W1T (coalesced stream) ----
  {
    int ks2 = tid >> 6, dq = tid & 63;  // 8 k-segments of 32, output dim-quad
    const float4* WT4b = (const float4*)WT2;       // [k*64 + dq]
    const float* h0 = hn_s[0]; const float* h1 = hn_s[1];
    float4 p0 = {0,0,0,0}, p1 = {0,0,0,0};
    int k0 = ks2 * 32;
    #pragma unroll 8
    for (int kk = 0; kk < 32; kk++){
      int k = k0 + kk;
      float4 wv = WT4b[k * 64 + dq];
      float a0v = h0[k], a1v = h1[k];   // wave-uniform -> LDS broadcast
      p0.x = fmaf(a0v, wv.x, p0.x); p0.y = fmaf(a0v, wv.y, p0.y);
      p0.z = fmaf(a0v, wv.z, p0.z); p0.w = fmaf(a0v, wv.w, p0.w);
      p1.x = fmaf(a1v, wv.x, p1.x); p1.y = fmaf(a1v, wv.y, p1.y);
      p1.z = fmaf(a1v, wv.z, p1.z); p1.w = fmaf(a1v, wv.w, p1.w);
    }
    parts[(ks2 * 64 + dq) * 2 + 0] = p0;
    parts[(ks2 * 64 + dq) * 2 + 1] = p1;
  }
  __syncthreads();
  {
    int rr = tid >> 8, d = tid & 255;   // waves 0-3: row 0, waves 4-7: row 1
    const float* pf2 = (const float*)parts;        // seg stride = 512 floats
    int base = ((d >> 2) * 2 + rr) * 4 + (d & 3);
    float q0 = pf2[base]        + pf2[base + 512];
    float q1 = pf2[base + 1024] + pf2[base + 1536];
    float q2 = pf2[base + 2048] + pf2[base + 2560];
    float q3 = pf2[base + 3072] + pf2[base + 3584];
    float mx = (q0 + q1) + (q2 + q3);
    double m2 = (double)mx * (double)mx;
    #pragma unroll
    for (int o = 32; o > 0; o >>= 1) m2 += __shfl_down(m2, o);
    int w2 = tid >> 6, lane2 = tid & 63;
    if (lane2 == 0) ssum[w2] = m2;
    __syncthreads();
    int b4 = rr * 4;
    double m2sum = (ssum[b4] + ssum[b4 + 1]) + (ssum[b4 + 2] + ssum[b4 + 3]);
    double mn = sqrt(m2sum); if (mn < 1e-15) mn = 1e-15;
    double xn = sqrt(hnorm2[rr]); if (xn < 1e-15) xn = 1e-15;
    double th = tanh(mn / xn * artanh_clip(xn));
    float wv = (float)((double)mx * (th / mn));
    int irow = i0 + rr;
    Whn[irow * DD + d] = wv;
    WhTn[d * NN + irow] = wv;
    if (d == 0) r2n[irow] = th * th;
  }
}

extern "C" void kernel_launch(void* const* d_in, const int* in_sizes, int n_in,
                              void* d_out, int out_size, void* d_ws, size_t ws_size,
                              hipStream_t stream){
  const float* H_euc = (const float*)d_in[0];
  const float* W     = (const float*)d_in[1];
  const int*   A     = (const int*)d_in[2];
  float* out = (float*)d_out;

  float* Hf   = (float*)d_ws;              // N*D
  float* Hn   = Hf   + NN * DD;            // N*D
  float* Wh   = Hn   + NN * DD;            // N*D
  float* WhT  = Wh   + NN * DD;            // D*N
  float* Whb  = WhT  + NN * DD;            // N*D (layer-1 Wh)
  float* WhTb = Whb  + NN * DD;            // D*N
  float* W1T  = WhTb + NN * DD;            // D*D (transposed layer-1 W)
  double* r2  = (double*)(W1T + DD * DD);  // N
  double* r2b = r2 + NN;                   // N

  matvec0_k<<<NN / 2, DD, 0, stream>>>(H_euc, W, W + DD * DD, W1T, Hf, Wh, WhT, r2);
  fused_k<false><<<NN / 2, 2 * DD, 0, stream>>>(Wh, WhT, r2, A, Hf, W1T, Hn, Whb, WhTb, r2b);
  fused_k<true> <<<NN / 2, 2 * DD, 0, stream>>>(Whb, WhTb, r2b, A, Hn, nullptr, out, nullptr, nullptr, nullptr);
}